// Round 1
// baseline (192.410 us; speedup 1.0000x reference)
//
#include <hip/hip_runtime.h>

#define BB 16
#define SS 128
#define DD 256
#define KK 12
#define NN 128
#define WW 116

// One 128-thread block per (b,w). Thread n owns negative n for all 12 k.
// predictions rows for this block are wave-uniform -> scalar loads (SGPR),
// latent negative row is per-lane float4 stream (L2-resident, 2MB total).
__global__ __launch_bounds__(128, 4)
void cpc_main(const float* __restrict__ pred,
              const float* __restrict__ latent,
              const int* __restrict__ bidx,
              const int* __restrict__ sidx,
              float* __restrict__ out) {
    const int wg = blockIdx.x;          // b*W + w
    const int b  = wg / WW;
    const int w  = wg - b * WW;
    const int n  = threadIdx.x;         // 0..127 = negative index

    // ---- negative scores: thread n, all K ----
    const int i   = (b * NN + n) * WW + w;
    const int seq = (sidx[i] + w) & (SS - 1);
    const int ext = seq + bidx[i] * SS;
    const float* __restrict__ lrow = latent + (size_t)ext * DD;
    const float* __restrict__ prow = pred + (size_t)wg * KK * DD;  // block-uniform

    float acc[KK];
#pragma unroll
    for (int k = 0; k < KK; ++k) acc[k] = 0.f;

#pragma unroll 4
    for (int d = 0; d < DD; d += 4) {
        const float4 lv = *reinterpret_cast<const float4*>(lrow + d);
#pragma unroll
        for (int k = 0; k < KK; ++k) {
            const float4 pv = *reinterpret_cast<const float4*>(prow + k * DD + d);
            acc[k] = fmaf(pv.x, lv.x, acc[k]);
            acc[k] = fmaf(pv.y, lv.y, acc[k]);
            acc[k] = fmaf(pv.z, lv.z, acc[k]);
            acc[k] = fmaf(pv.w, lv.w, acc[k]);
        }
    }

    constexpr float inv_d = 1.0f / DD;
    __shared__ float sc[KK][NN + 1];   // +1 pad: k-stride 129 -> bank shift per k
    __shared__ float posv[KK];
#pragma unroll
    for (int k = 0; k < KK; ++k) sc[k][n] = acc[k] * inv_d;

    // ---- positive scores: 96 threads = 12 k-groups x 8 lanes ----
    const int t = threadIdx.x;
    if (t < 96) {
        const int k = t >> 3, g = t & 7;
        const float* pr = pred + ((size_t)wg * KK + k) * DD + g * 32;
        const float* lr = latent + ((size_t)b * SS + (w + k + 1)) * DD + g * 32;
        float s = 0.f;
#pragma unroll
        for (int d = 0; d < 32; d += 4) {
            const float4 pv = *reinterpret_cast<const float4*>(pr + d);
            const float4 lv = *reinterpret_cast<const float4*>(lr + d);
            s = fmaf(pv.x, lv.x, s); s = fmaf(pv.y, lv.y, s);
            s = fmaf(pv.z, lv.z, s); s = fmaf(pv.w, lv.w, s);
        }
        s += __shfl_xor(s, 1);
        s += __shfl_xor(s, 2);
        s += __shfl_xor(s, 4);
        if (g == 0) posv[k] = s * inv_d;
    }
    __syncthreads();

    // ---- logsumexp(129) + argmax==0 per k; 8 lanes per k ----
    if (t < 96) {
        const int k = t >> 3, g = t & 7;
        const float p = posv[k];
        float v[16];
        float m = p;                       // max over all 129 incl. pos
#pragma unroll
        for (int j = 0; j < 16; ++j) {
            v[j] = sc[k][j * 8 + g];
            m = fmaxf(m, v[j]);
        }
        m = fmaxf(m, __shfl_xor(m, 1));
        m = fmaxf(m, __shfl_xor(m, 2));
        m = fmaxf(m, __shfl_xor(m, 4));
        float sum = (g == 0) ? __expf(p - m) : 0.f;   // pos term counted once
#pragma unroll
        for (int j = 0; j < 16; ++j) sum += __expf(v[j] - m);
        sum += __shfl_xor(sum, 1);
        sum += __shfl_xor(sum, 2);
        sum += __shfl_xor(sum, 4);
        if (g == 0) {
            constexpr float inv_bw = 1.0f / (BB * WW);
            const float lse = m + __logf(sum);
            atomicAdd(&out[k], (lse - p) * inv_bw);
            // argmax==0 <=> pos >= max of all 129 (ties pick index 0)
            atomicAdd(&out[KK + k], (p >= m) ? inv_bw : 0.f);
        }
    }
}

extern "C" void kernel_launch(void* const* d_in, const int* in_sizes, int n_in,
                              void* d_out, int out_size, void* d_ws, size_t ws_size,
                              hipStream_t stream) {
    const float* pred   = (const float*)d_in[0];
    const float* latent = (const float*)d_in[1];
    const int*   bidx   = (const int*)d_in[2];
    const int*   sidx   = (const int*)d_in[3];
    float* out = (float*)d_out;
    hipMemsetAsync(out, 0, 2 * KK * sizeof(float), stream);
    cpc_main<<<BB * WW, 128, 0, stream>>>(pred, latent, bidx, sidx, out);
}

// Round 6
// 170.851 us; speedup vs baseline: 1.1262x; 1.1262x over previous
//
#include <hip/hip_runtime.h>

#define BB 16
#define SS 128
#define DD 256
#define KK 12
#define NN 128
#define WW 116

// One 256-thread block per (b,w).
// Stage 1: cooperative copy of the block's 12x256 fp32 pred tile into LDS
//          (12 KB) — R0 re-read this tile 128x per block through L1 (~1.7 MB
//          L1 traffic/block), the likely real bottleneck.
// Stage 2: thread (n,h) computes d-half h of the 12 dots for negative n.
//          pred comes from LDS at wave-uniform addresses (broadcast, free);
//          latent row-half is a per-lane float4 stream (L2-resident).
// Stage 3: halves combine through LDS; positives + logsumexp epilogue.
__global__ __launch_bounds__(256, 6)
void cpc_main(const float* __restrict__ pred,
              const float* __restrict__ latent,
              const int* __restrict__ bidx,
              const int* __restrict__ sidx,
              float* __restrict__ out) {
    const int wg = blockIdx.x;          // b*W + w
    const int b  = wg / WW;
    const int w  = wg - b * WW;
    const int t  = threadIdx.x;
    const int n  = t & (NN - 1);        // negative index
    const int h  = t >> 7;              // d-half: 0 or 1

    __shared__ float predl[KK * DD];    // 12 KB
    __shared__ float sc[KK][NN + 1];    // +1 pad
    __shared__ float posv[KK];

    // ---- stage pred tile: 3 float4 per thread, coalesced ----
    {
        const float4* __restrict__ psrc =
            reinterpret_cast<const float4*>(pred + (size_t)wg * KK * DD);
        float4* pdst = reinterpret_cast<float4*>(predl);
#pragma unroll
        for (int i = 0; i < 3; ++i) pdst[t + i * 256] = psrc[t + i * 256];
    }
    __syncthreads();

    // ---- negative partial scores: thread (n,h), all K, 128 d's ----
    const int i   = (b * NN + n) * WW + w;
    const int seq = (sidx[i] + w) & (SS - 1);
    const int ext = seq + bidx[i] * SS;
    const float* __restrict__ lrow = latent + (size_t)ext * DD + h * (DD / 2);
    const float* __restrict__ prow = predl + h * (DD / 2);   // LDS, wave-uniform

    float acc[KK];
#pragma unroll
    for (int k = 0; k < KK; ++k) acc[k] = 0.f;

#pragma unroll 4
    for (int d = 0; d < DD / 2; d += 4) {
        const float4 lv = *reinterpret_cast<const float4*>(lrow + d);
#pragma unroll
        for (int k = 0; k < KK; ++k) {
            const float4 pv = *reinterpret_cast<const float4*>(prow + k * DD + d);
            acc[k] = fmaf(pv.x, lv.x, acc[k]);
            acc[k] = fmaf(pv.y, lv.y, acc[k]);
            acc[k] = fmaf(pv.z, lv.z, acc[k]);
            acc[k] = fmaf(pv.w, lv.w, acc[k]);
        }
    }

    constexpr float inv_d = 1.0f / DD;
    if (h == 1) {
#pragma unroll
        for (int k = 0; k < KK; ++k) sc[k][n] = acc[k];
    }
    __syncthreads();
    if (h == 0) {
#pragma unroll
        for (int k = 0; k < KK; ++k) sc[k][n] = (acc[k] + sc[k][n]) * inv_d;
    }

    // ---- positive scores on h=1 threads (overlaps h=0 combine) ----
    if (t >= 128 && t < 224) {
        const int tt = t - 128;
        const int k = tt >> 3, g = tt & 7;
        const float* pr = predl + k * DD + g * 32;          // LDS
        const float* lr = latent + ((size_t)b * SS + (w + k + 1)) * DD + g * 32;
        float s = 0.f;
#pragma unroll
        for (int d = 0; d < 32; d += 4) {
            const float4 pv = *reinterpret_cast<const float4*>(pr + d);
            const float4 lv = *reinterpret_cast<const float4*>(lr + d);
            s = fmaf(pv.x, lv.x, s); s = fmaf(pv.y, lv.y, s);
            s = fmaf(pv.z, lv.z, s); s = fmaf(pv.w, lv.w, s);
        }
        s += __shfl_xor(s, 1);
        s += __shfl_xor(s, 2);
        s += __shfl_xor(s, 4);
        if (g == 0) posv[k] = s * inv_d;
    }
    __syncthreads();

    // ---- logsumexp(129) + argmax==0 per k; 8 lanes per k ----
    if (t < 96) {
        const int k = t >> 3, g = t & 7;
        const float p = posv[k];
        float v[16];
        float m = p;                       // max over all 129 incl. pos
#pragma unroll
        for (int j = 0; j < 16; ++j) {
            v[j] = sc[k][j * 8 + g];
            m = fmaxf(m, v[j]);
        }
        m = fmaxf(m, __shfl_xor(m, 1));
        m = fmaxf(m, __shfl_xor(m, 2));
        m = fmaxf(m, __shfl_xor(m, 4));
        float sum = (g == 0) ? __expf(p - m) : 0.f;   // pos term counted once
#pragma unroll
        for (int j = 0; j < 16; ++j) sum += __expf(v[j] - m);
        sum += __shfl_xor(sum, 1);
        sum += __shfl_xor(sum, 2);
        sum += __shfl_xor(sum, 4);
        if (g == 0) {
            constexpr float inv_bw = 1.0f / (BB * WW);
            const float lse = m + __logf(sum);
            atomicAdd(&out[k], (lse - p) * inv_bw);
            // argmax==0 <=> pos >= max of all 129 (ties pick index 0)
            atomicAdd(&out[KK + k], (p >= m) ? inv_bw : 0.f);
        }
    }
}

extern "C" void kernel_launch(void* const* d_in, const int* in_sizes, int n_in,
                              void* d_out, int out_size, void* d_ws, size_t ws_size,
                              hipStream_t stream) {
    const float* pred   = (const float*)d_in[0];
    const float* latent = (const float*)d_in[1];
    const int*   bidx   = (const int*)d_in[2];
    const int*   sidx   = (const int*)d_in[3];
    float* out = (float*)d_out;
    hipMemsetAsync(out, 0, 2 * KK * sizeof(float), stream);
    cpc_main<<<BB * WW, 256, 0, stream>>>(pred, latent, bidx, sidx, out);
}